// Round 23
// baseline (217.331 us; speedup 1.0000x reference)
//
#include <hip/hip_runtime.h>

#define N_NODES 100000
#define NT (2 * N_NODES)             // stacked nodes (conv1 then conv2)
#define D 128
#define N_EDGES 600000
#define ET (2 * N_EDGES)
#define SCAN_B 256
#define NBLK2 ((NT + SCAN_B - 1) / SCAN_B)   // 782
#define FROWS 256                            // rows per fused block (16 waves)
#define FBLK ((N_NODES + FROWS - 1) / FROWS) // 391
#define XBLK 12500                           // x2bf blocks
#define EGRID ((ET + 255) / 256)             // 4688 degree blocks
#define NPART 8                              // XCD partitions for csr_fill
#define PRNG (NT / NPART)                    // 25000 stacked nodes per partition
#define CBLK 512                             // csr_fill blocks per partition

typedef __attribute__((ext_vector_type(8))) short bf16x8;
typedef __attribute__((ext_vector_type(4))) float f32x4;

__device__ __forceinline__ unsigned short f2bf(float f) {
    union { float f; unsigned u; } v; v.f = f;
    unsigned r = (v.u + 0x7fff + ((v.u >> 16) & 1)) >> 16;   // RNE
    return (unsigned short)r;
}
__device__ __forceinline__ float bf2f(unsigned short h) {
    union { unsigned u; float f; } v; v.u = ((unsigned)h) << 16;
    return v.f;
}

// ---------- edge index dtype handling ----------
__device__ __forceinline__ long long load_idx(const void* e, long long i, int is32) {
    if (is32) return (long long)((const int*)e)[i];
    return ((const long long*)e)[i];
}

// per-wave redundant dtype detect: 64 L2-hot samples, no cross-kernel dependency
__device__ __forceinline__ int self_detect(const unsigned long long* __restrict__ e) {
    unsigned long long v = e[threadIdx.x & 63];
    unsigned long long m = __ballot(v > 0xFFFFFFFFull);
    return (m != 0ull) ? 1 : 0;
}

// ---------- K1: Mt (0..127) | bt (128) | x2bf (129..12628) | degree (rest) ----------
__global__ void prep_x2bf_degree(const float* __restrict__ W1, const float* __restrict__ W2,
                                 const float* __restrict__ weight,
                                 const float* __restrict__ b1, const float* __restrict__ b2,
                                 const float* __restrict__ bias,
                                 const float* __restrict__ x, unsigned short* __restrict__ xb,
                                 const void* __restrict__ ep, const void* __restrict__ en,
                                 unsigned short* __restrict__ Mt, float* __restrict__ bt,
                                 int* __restrict__ degi) {
    const int b = blockIdx.x;
    if (b < 128) {
        // Mt[j][k] bf16: j=out col (128), k=stacked contraction (256)
        int idx = b * 256 + threadIdx.x;
        int j = idx >> 8, k = idx & 255;
        float a = 0.f;
        if (k < D) {
            for (int d = 0; d < D; ++d) a += W1[k * D + d] * weight[d * D + j];
        } else {
            for (int d = 0; d < D; ++d) a += W2[(k - D) * D + d] * weight[(D + d) * D + j];
        }
        Mt[j * 256 + k] = f2bf(a);
    } else if (b == 128) {
        int t = threadIdx.x;
        if (t < D) {
            float a = bias[t];
            for (int k = 0; k < D; ++k)
                a += b1[k] * weight[k * D + t] + b2[k] * weight[(D + k) * D + t];
            bt[t] = a;
        }
    } else if (b < 129 + XBLK) {
        long long t = (long long)(b - 129) * 256 + threadIdx.x;   // N*32 float4 slots
        float4 a = ((const float4*)x)[t];
        ((ushort4*)xb)[t] = make_ushort4(f2bf(a.x), f2bf(a.y), f2bf(a.z), f2bf(a.w));
    } else {
        int is32 = self_detect((const unsigned long long*)ep);
        int i = (b - 129 - XBLK) * 256 + threadIdx.x;
        if (i >= ET) return;
        int conv = (i >= N_EDGES);
        const void* e = conv ? en : ep;
        int j = conv ? i - N_EDGES : i;
        long long d = load_idx(e, (long long)N_EDGES + j, is32);
        atomicAdd(&degi[conv * N_NODES + (int)d], 1);
    }
}

// ---------- scan pass1 over NT (+ fused dinv + u8 degree cache) ----------
__global__ void scan_pass1(const int* __restrict__ degi, int* __restrict__ bsum,
                           float* __restrict__ dinv, unsigned char* __restrict__ degb) {
    __shared__ int sm[SCAN_B];
    int i = blockIdx.x * SCAN_B + threadIdx.x;
    int v = (i < NT) ? degi[i] : 0;
    if (i < NT) {
        dinv[i] = rsqrtf((float)v + 1.0f);
        degb[i] = (unsigned char)(v > 255 ? 255 : v);   // deg>255 statistically impossible
    }
    sm[threadIdx.x] = v;
    __syncthreads();
    for (int s = SCAN_B / 2; s > 0; s >>= 1) {
        if (threadIdx.x < s) sm[threadIdx.x] += sm[threadIdx.x + s];
        __syncthreads();
    }
    if (threadIdx.x == 0) bsum[blockIdx.x] = sm[0];
}

// ---------- scan pass3 with self-computed base ----------
__global__ void scan_pass3(const int* __restrict__ degi, const int* __restrict__ bsum,
                           int* __restrict__ off) {
    __shared__ int red[SCAN_B];
    __shared__ int sm[SCAN_B];
    int partial = 0;
    for (int i = threadIdx.x; i < blockIdx.x; i += SCAN_B) partial += bsum[i];
    red[threadIdx.x] = partial;
    __syncthreads();
    for (int s = SCAN_B / 2; s > 0; s >>= 1) {
        if (threadIdx.x < s) red[threadIdx.x] += red[threadIdx.x + s];
        __syncthreads();
    }
    int base = red[0];
    int i = blockIdx.x * SCAN_B + threadIdx.x;
    int v = (i < NT) ? degi[i] : 0;
    sm[threadIdx.x] = v;
    __syncthreads();
    for (int ofs = 1; ofs < SCAN_B; ofs <<= 1) {
        int add = (threadIdx.x >= ofs) ? sm[threadIdx.x - ofs] : 0;
        __syncthreads();
        sm[threadIdx.x] += add;
        __syncthreads();
    }
    int excl = sm[threadIdx.x] - v + base;
    if (i < NT) off[i] = excl;
    if (i == NT - 1) off[NT] = excl + v;
}

// ---------- CSR fill, XCD-partitioned by dst range (R17: pipeline −6µs) ----------
__global__ void csr_fill_xcd(const void* __restrict__ ep_, const void* __restrict__ en_,
                             const int* __restrict__ off, int* __restrict__ degi,
                             const unsigned char* __restrict__ degb,
                             unsigned* __restrict__ csr) {
    int is32 = self_detect((const unsigned long long*)ep_);
    int P = blockIdx.x & (NPART - 1);
    int bi = blockIdx.x >> 3;
    int lo = P * PRNG, hi = lo + PRNG;
    for (int i = bi * 256 + threadIdx.x; i < ET; i += CBLK * 256) {
        int conv = (i >= N_EDGES);
        const void* e = conv ? en_ : ep_;
        int j = conv ? i - N_EDGES : i;
        int di = (int)load_idx(e, (long long)N_EDGES + j, is32);
        int node = conv * N_NODES + di;
        if (node < lo || node >= hi) continue;
        int si = (int)load_idx(e, j, is32);
        int pos = off[node] + atomicSub(&degi[node], 1) - 1;   // countdown deg-1..0
        unsigned degS = degb[conv * N_NODES + si];
        csr[pos] = (unsigned)si | (degS << 20);
    }
}

// ---------- fused gather + GEMM (R22 base + nontemporal csr/out streams) ----------
// 1024 threads = 16 waves, one 66KB Mt LDS copy; wave w owns rows [blk*256+16w,+16).
// Lane l (rl=l&15, q=l>>4) gathers row blk*256+16w+rl, cols q*8+{0,32,64,96}.
// R23: csr (read-once stream) loads and out (write-once stream) stores are
// NONTEMPORAL — they no longer allocate in L2, preserving L2 for xb (the only
// reused data). Mechanism: 51MB out + 4.8MB csr per dispatch were evicting the
// 25.6MB xb table from the 4MB-per-XCD L2s.
__global__ __launch_bounds__(1024) void fused_gather_gemm(
    const int* __restrict__ off, const unsigned* __restrict__ csr,
    const unsigned short* __restrict__ xb, const float* __restrict__ dinv,
    const unsigned short* __restrict__ Mt, const float* __restrict__ bt,
    float* __restrict__ out) {
    __shared__ unsigned short mlds[128][264];   // +8 pad
    int t = threadIdx.x;
    for (int c = t; c < 4096; c += 1024) {
        int row = c >> 5;
        int kc = (c & 31) * 8;
        *(ulonglong2*)&mlds[row][kc] = *(const ulonglong2*)&Mt[row * 256 + kc];
    }
    __syncthreads();

    int wave = t >> 6, lane = t & 63;
    int rl = lane & 15, q = lane >> 4;
    int gr = blockIdx.x * FROWS + wave * 16 + rl;        // gathered row
    const bool valid = gr < N_NODES;

    bf16x8 af[8];
    #pragma unroll
    for (int conv = 0; conv < 2; ++conv) {
        float acc[4][8];
        if (valid) {
            int n = conv * N_NODES + gr;
            float dn = dinv[n];
            float f = dn * dn;
            const unsigned short* xr = xb + (size_t)gr * D + q * 8;
            #pragma unroll
            for (int m = 0; m < 4; ++m) {
                bf16x8 v = *(const bf16x8*)(xr + m * 32);
                #pragma unroll
                for (int j = 0; j < 8; ++j) acc[m][j] = bf2f((unsigned short)v[j]) * f;
            }
            int e0 = off[n], e1 = off[n + 1];
            int e = e0;
            unsigned c0 = 0, c1 = 0;
            if (e + 1 < e1) {
                c0 = __builtin_nontemporal_load(&csr[e]);
                c1 = __builtin_nontemporal_load(&csr[e + 1]);
            }
            for (; e + 1 < e1; ) {
                // prefetch NEXT pair before this iteration's FMAs
                int e2 = e + 2;
                unsigned n0 = 0, n1 = 0;
                if (e2 + 1 < e1) {
                    n0 = __builtin_nontemporal_load(&csr[e2]);
                    n1 = __builtin_nontemporal_load(&csr[e2 + 1]);
                }
                const unsigned short* p0 = xb + (size_t)(c0 & 0xFFFFF) * D + q * 8;
                const unsigned short* p1 = xb + (size_t)(c1 & 0xFFFFF) * D + q * 8;
                bf16x8 a0 = *(const bf16x8*)(p0);
                bf16x8 a1 = *(const bf16x8*)(p0 + 32);
                bf16x8 a2 = *(const bf16x8*)(p0 + 64);
                bf16x8 a3 = *(const bf16x8*)(p0 + 96);
                bf16x8 b0 = *(const bf16x8*)(p1);
                bf16x8 b1 = *(const bf16x8*)(p1 + 32);
                bf16x8 b2 = *(const bf16x8*)(p1 + 64);
                bf16x8 b3 = *(const bf16x8*)(p1 + 96);
                float coef0 = dn * rsqrtf((float)(c0 >> 20) + 1.0f);
                float coef1 = dn * rsqrtf((float)(c1 >> 20) + 1.0f);
                #pragma unroll
                for (int j = 0; j < 8; ++j) {
                    acc[0][j] += coef0 * bf2f((unsigned short)a0[j]);
                    acc[1][j] += coef0 * bf2f((unsigned short)a1[j]);
                    acc[2][j] += coef0 * bf2f((unsigned short)a2[j]);
                    acc[3][j] += coef0 * bf2f((unsigned short)a3[j]);
                }
                #pragma unroll
                for (int j = 0; j < 8; ++j) {
                    acc[0][j] += coef1 * bf2f((unsigned short)b0[j]);
                    acc[1][j] += coef1 * bf2f((unsigned short)b1[j]);
                    acc[2][j] += coef1 * bf2f((unsigned short)b2[j]);
                    acc[3][j] += coef1 * bf2f((unsigned short)b3[j]);
                }
                c0 = n0; c1 = n1;
                e = e2;
            }
            if (e < e1) {
                unsigned cc = __builtin_nontemporal_load(&csr[e]);
                const unsigned short* p0 = xb + (size_t)(cc & 0xFFFFF) * D + q * 8;
                bf16x8 a0 = *(const bf16x8*)(p0);
                bf16x8 a1 = *(const bf16x8*)(p0 + 32);
                bf16x8 a2 = *(const bf16x8*)(p0 + 64);
                bf16x8 a3 = *(const bf16x8*)(p0 + 96);
                float coef0 = dn * rsqrtf((float)(cc >> 20) + 1.0f);
                #pragma unroll
                for (int j = 0; j < 8; ++j) {
                    acc[0][j] += coef0 * bf2f((unsigned short)a0[j]);
                    acc[1][j] += coef0 * bf2f((unsigned short)a1[j]);
                    acc[2][j] += coef0 * bf2f((unsigned short)a2[j]);
                    acc[3][j] += coef0 * bf2f((unsigned short)a3[j]);
                }
            }
        } else {
            #pragma unroll
            for (int m = 0; m < 4; ++m)
                #pragma unroll
                for (int j = 0; j < 8; ++j) acc[m][j] = 0.f;
        }
        #pragma unroll
        for (int m = 0; m < 4; ++m) {
            bf16x8 a;
            #pragma unroll
            for (int j = 0; j < 8; ++j) a[j] = (short)f2bf(acc[m][j]);
            af[conv * 4 + m] = a;
        }
    }

    f32x4 C[8];
    #pragma unroll
    for (int i = 0; i < 8; ++i) C[i] = (f32x4){0.f, 0.f, 0.f, 0.f};
    #pragma unroll
    for (int ks = 0; ks < 8; ++ks) {
        bf16x8 afr = af[ks];          // ks 0..3 -> conv1 k-blocks, 4..7 -> conv2
        #pragma unroll
        for (int ct = 0; ct < 8; ++ct) {
            bf16x8 bfr = *(const bf16x8*)&mlds[ct * 16 + rl][ks * 32 + q * 8];
            C[ct] = __builtin_amdgcn_mfma_f32_16x16x32_bf16(afr, bfr, C[ct], 0, 0, 0);
        }
    }

    // C/D layout: col = lane&15, row = (lane>>4)*4 + reg — nontemporal stores
    int orow = blockIdx.x * FROWS + wave * 16 + q * 4;
    #pragma unroll
    for (int ct = 0; ct < 8; ++ct) {
        int col = ct * 16 + rl;
        float b = bt[col];
        #pragma unroll
        for (int reg = 0; reg < 4; ++reg) {
            int row = orow + reg;
            if (row < N_NODES)
                __builtin_nontemporal_store(C[ct][reg] + b, &out[(long long)row * D + col]);
        }
    }
}

extern "C" void kernel_launch(void* const* d_in, const int* in_sizes, int n_in,
                              void* d_out, int out_size, void* d_ws, size_t ws_size,
                              hipStream_t stream) {
    const float* x      = (const float*)d_in[0];
    const void*  e_pos  = d_in[1];
    const void*  e_neg  = d_in[2];
    const float* W1     = (const float*)d_in[3];
    const float* b1     = (const float*)d_in[4];
    const float* W2     = (const float*)d_in[5];
    const float* b2     = (const float*)d_in[6];
    const float* weight = (const float*)d_in[7];
    const float* bias   = (const float*)d_in[8];
    float* out = (float*)d_out;

    // ---- workspace layout (~33 MB) ----
    unsigned short* xb = (unsigned short*)d_ws;          // N*D bf16
    unsigned short* Mt = xb + (size_t)N_NODES * D;       // 128*256
    float* bt   = (float*)(Mt + 128 * 256);              // D
    float* dinv = bt + D;                                // NT
    int*   degi = (int*)(dinv + NT);                     // NT
    int*   off  = degi + NT;                             // NT+4 (pad)
    int*   bsum = off + NT + 4;                          // 1024
    unsigned char* degb = (unsigned char*)(bsum + 1024); // NT bytes
    unsigned* csr = (unsigned*)(degb + NT);              // ET (4B entries)

    hipMemsetAsync(degi, 0, NT * sizeof(int), stream);
    prep_x2bf_degree<<<129 + XBLK + EGRID, 256, 0, stream>>>(
        W1, W2, weight, b1, b2, bias, x, xb, e_pos, e_neg, Mt, bt, degi);
    scan_pass1<<<NBLK2, SCAN_B, 0, stream>>>(degi, bsum, dinv, degb);
    scan_pass3<<<NBLK2, SCAN_B, 0, stream>>>(degi, bsum, off);
    csr_fill_xcd<<<NPART * CBLK, 256, 0, stream>>>(e_pos, e_neg, off, degi, degb, csr);
    fused_gather_gemm<<<FBLK, 1024, 0, stream>>>(off, csr, xb, dinv, Mt, bt, out);
}

// Round 24
// 211.590 us; speedup vs baseline: 1.0271x; 1.0271x over previous
//
#include <hip/hip_runtime.h>

#define N_NODES 100000
#define NT (2 * N_NODES)             // stacked nodes (conv1 then conv2)
#define D 128
#define N_EDGES 600000
#define ET (2 * N_EDGES)
#define SCAN_B 256
#define NBLK2 ((NT + SCAN_B - 1) / SCAN_B)   // 782
#define FROWS 256                            // rows per fused block (16 waves)
#define FBLK ((N_NODES + FROWS - 1) / FROWS) // 391
#define XBLK 12500                           // x2bf blocks
#define EGRID ((ET + 255) / 256)             // 4688 degree blocks
#define NPART 8                              // XCD partitions for csr_fill
#define PRNG (NT / NPART)                    // 25000 stacked nodes per partition
#define CBLK 512                             // csr_fill blocks per partition

typedef __attribute__((ext_vector_type(8))) short bf16x8;
typedef __attribute__((ext_vector_type(4))) float f32x4;

__device__ __forceinline__ unsigned short f2bf(float f) {
    union { float f; unsigned u; } v; v.f = f;
    unsigned r = (v.u + 0x7fff + ((v.u >> 16) & 1)) >> 16;   // RNE
    return (unsigned short)r;
}
__device__ __forceinline__ float bf2f(unsigned short h) {
    union { unsigned u; float f; } v; v.u = ((unsigned)h) << 16;
    return v.f;
}

// ---------- edge index dtype handling ----------
__device__ __forceinline__ long long load_idx(const void* e, long long i, int is32) {
    if (is32) return (long long)((const int*)e)[i];
    return ((const long long*)e)[i];
}

// per-wave redundant dtype detect: 64 L2-hot samples, no cross-kernel dependency
__device__ __forceinline__ int self_detect(const unsigned long long* __restrict__ e) {
    unsigned long long v = e[threadIdx.x & 63];
    unsigned long long m = __ballot(v > 0xFFFFFFFFull);
    return (m != 0ull) ? 1 : 0;
}

// ---------- K1: Mt (0..127) | bt (128) | x2bf (129..12628) | degree (rest) ----------
__global__ void prep_x2bf_degree(const float* __restrict__ W1, const float* __restrict__ W2,
                                 const float* __restrict__ weight,
                                 const float* __restrict__ b1, const float* __restrict__ b2,
                                 const float* __restrict__ bias,
                                 const float* __restrict__ x, unsigned short* __restrict__ xb,
                                 const void* __restrict__ ep, const void* __restrict__ en,
                                 unsigned short* __restrict__ Mt, float* __restrict__ bt,
                                 int* __restrict__ degi) {
    const int b = blockIdx.x;
    if (b < 128) {
        // Mt[j][k] bf16: j=out col (128), k=stacked contraction (256)
        int idx = b * 256 + threadIdx.x;
        int j = idx >> 8, k = idx & 255;
        float a = 0.f;
        if (k < D) {
            for (int d = 0; d < D; ++d) a += W1[k * D + d] * weight[d * D + j];
        } else {
            for (int d = 0; d < D; ++d) a += W2[(k - D) * D + d] * weight[(D + d) * D + j];
        }
        Mt[j * 256 + k] = f2bf(a);
    } else if (b == 128) {
        int t = threadIdx.x;
        if (t < D) {
            float a = bias[t];
            for (int k = 0; k < D; ++k)
                a += b1[k] * weight[k * D + t] + b2[k] * weight[(D + k) * D + t];
            bt[t] = a;
        }
    } else if (b < 129 + XBLK) {
        long long t = (long long)(b - 129) * 256 + threadIdx.x;   // N*32 float4 slots
        float4 a = ((const float4*)x)[t];
        ((ushort4*)xb)[t] = make_ushort4(f2bf(a.x), f2bf(a.y), f2bf(a.z), f2bf(a.w));
    } else {
        int is32 = self_detect((const unsigned long long*)ep);
        int i = (b - 129 - XBLK) * 256 + threadIdx.x;
        if (i >= ET) return;
        int conv = (i >= N_EDGES);
        const void* e = conv ? en : ep;
        int j = conv ? i - N_EDGES : i;
        long long d = load_idx(e, (long long)N_EDGES + j, is32);
        atomicAdd(&degi[conv * N_NODES + (int)d], 1);
    }
}

// ---------- scan pass1 over NT (+ fused dinv + u8 degree cache) ----------
__global__ void scan_pass1(const int* __restrict__ degi, int* __restrict__ bsum,
                           float* __restrict__ dinv, unsigned char* __restrict__ degb) {
    __shared__ int sm[SCAN_B];
    int i = blockIdx.x * SCAN_B + threadIdx.x;
    int v = (i < NT) ? degi[i] : 0;
    if (i < NT) {
        dinv[i] = rsqrtf((float)v + 1.0f);
        degb[i] = (unsigned char)(v > 255 ? 255 : v);   // deg>255 statistically impossible
    }
    sm[threadIdx.x] = v;
    __syncthreads();
    for (int s = SCAN_B / 2; s > 0; s >>= 1) {
        if (threadIdx.x < s) sm[threadIdx.x] += sm[threadIdx.x + s];
        __syncthreads();
    }
    if (threadIdx.x == 0) bsum[blockIdx.x] = sm[0];
}

// ---------- scan pass3 with self-computed base ----------
__global__ void scan_pass3(const int* __restrict__ degi, const int* __restrict__ bsum,
                           int* __restrict__ off) {
    __shared__ int red[SCAN_B];
    __shared__ int sm[SCAN_B];
    int partial = 0;
    for (int i = threadIdx.x; i < blockIdx.x; i += SCAN_B) partial += bsum[i];
    red[threadIdx.x] = partial;
    __syncthreads();
    for (int s = SCAN_B / 2; s > 0; s >>= 1) {
        if (threadIdx.x < s) red[threadIdx.x] += red[threadIdx.x + s];
        __syncthreads();
    }
    int base = red[0];
    int i = blockIdx.x * SCAN_B + threadIdx.x;
    int v = (i < NT) ? degi[i] : 0;
    sm[threadIdx.x] = v;
    __syncthreads();
    for (int ofs = 1; ofs < SCAN_B; ofs <<= 1) {
        int add = (threadIdx.x >= ofs) ? sm[threadIdx.x - ofs] : 0;
        __syncthreads();
        sm[threadIdx.x] += add;
        __syncthreads();
    }
    int excl = sm[threadIdx.x] - v + base;
    if (i < NT) off[i] = excl;
    if (i == NT - 1) off[NT] = excl + v;
}

// ---------- CSR fill, XCD-partitioned by dst range (R17: pipeline −6µs) ----------
__global__ void csr_fill_xcd(const void* __restrict__ ep_, const void* __restrict__ en_,
                             const int* __restrict__ off, int* __restrict__ degi,
                             const unsigned char* __restrict__ degb,
                             unsigned* __restrict__ csr) {
    int is32 = self_detect((const unsigned long long*)ep_);
    int P = blockIdx.x & (NPART - 1);
    int bi = blockIdx.x >> 3;
    int lo = P * PRNG, hi = lo + PRNG;
    for (int i = bi * 256 + threadIdx.x; i < ET; i += CBLK * 256) {
        int conv = (i >= N_EDGES);
        const void* e = conv ? en_ : ep_;
        int j = conv ? i - N_EDGES : i;
        int di = (int)load_idx(e, (long long)N_EDGES + j, is32);
        int node = conv * N_NODES + di;
        if (node < lo || node >= hi) continue;
        int si = (int)load_idx(e, j, is32);
        int pos = off[node] + atomicSub(&degi[node], 1) - 1;   // countdown deg-1..0
        unsigned degS = degb[conv * N_NODES + si];
        csr[pos] = (unsigned)si | (degS << 20);
    }
}

// ---------- fused gather + GEMM (R22-proven optimum: csr-pair software pipeline) ----------
// 1024 threads = 16 waves, one 66KB Mt LDS copy; wave w owns rows [blk*256+16w,+16).
// Lane l (rl=l&15, q=l>>4) gathers row blk*256+16w+rl, cols q*8+{0,32,64,96}.
// R23 lesson: nontemporal csr/out hints REGRESS (nt stores defeat L2 write-
// coalescing of the per-lane 4B C-writes: WRITE 50->62MB). Plain loads/stores.
__global__ __launch_bounds__(1024) void fused_gather_gemm(
    const int* __restrict__ off, const unsigned* __restrict__ csr,
    const unsigned short* __restrict__ xb, const float* __restrict__ dinv,
    const unsigned short* __restrict__ Mt, const float* __restrict__ bt,
    float* __restrict__ out) {
    __shared__ unsigned short mlds[128][264];   // +8 pad
    int t = threadIdx.x;
    for (int c = t; c < 4096; c += 1024) {
        int row = c >> 5;
        int kc = (c & 31) * 8;
        *(ulonglong2*)&mlds[row][kc] = *(const ulonglong2*)&Mt[row * 256 + kc];
    }
    __syncthreads();

    int wave = t >> 6, lane = t & 63;
    int rl = lane & 15, q = lane >> 4;
    int gr = blockIdx.x * FROWS + wave * 16 + rl;        // gathered row
    const bool valid = gr < N_NODES;

    bf16x8 af[8];
    #pragma unroll
    for (int conv = 0; conv < 2; ++conv) {
        float acc[4][8];
        if (valid) {
            int n = conv * N_NODES + gr;
            float dn = dinv[n];
            float f = dn * dn;
            const unsigned short* xr = xb + (size_t)gr * D + q * 8;
            #pragma unroll
            for (int m = 0; m < 4; ++m) {
                bf16x8 v = *(const bf16x8*)(xr + m * 32);
                #pragma unroll
                for (int j = 0; j < 8; ++j) acc[m][j] = bf2f((unsigned short)v[j]) * f;
            }
            int e0 = off[n], e1 = off[n + 1];
            int e = e0;
            unsigned c0 = 0, c1 = 0;
            if (e + 1 < e1) { c0 = csr[e]; c1 = csr[e + 1]; }   // prologue pair
            for (; e + 1 < e1; ) {
                // prefetch NEXT pair before this iteration's FMAs
                int e2 = e + 2;
                unsigned n0 = 0, n1 = 0;
                if (e2 + 1 < e1) { n0 = csr[e2]; n1 = csr[e2 + 1]; }
                const unsigned short* p0 = xb + (size_t)(c0 & 0xFFFFF) * D + q * 8;
                const unsigned short* p1 = xb + (size_t)(c1 & 0xFFFFF) * D + q * 8;
                bf16x8 a0 = *(const bf16x8*)(p0);
                bf16x8 a1 = *(const bf16x8*)(p0 + 32);
                bf16x8 a2 = *(const bf16x8*)(p0 + 64);
                bf16x8 a3 = *(const bf16x8*)(p0 + 96);
                bf16x8 b0 = *(const bf16x8*)(p1);
                bf16x8 b1 = *(const bf16x8*)(p1 + 32);
                bf16x8 b2 = *(const bf16x8*)(p1 + 64);
                bf16x8 b3 = *(const bf16x8*)(p1 + 96);
                float coef0 = dn * rsqrtf((float)(c0 >> 20) + 1.0f);
                float coef1 = dn * rsqrtf((float)(c1 >> 20) + 1.0f);
                #pragma unroll
                for (int j = 0; j < 8; ++j) {
                    acc[0][j] += coef0 * bf2f((unsigned short)a0[j]);
                    acc[1][j] += coef0 * bf2f((unsigned short)a1[j]);
                    acc[2][j] += coef0 * bf2f((unsigned short)a2[j]);
                    acc[3][j] += coef0 * bf2f((unsigned short)a3[j]);
                }
                #pragma unroll
                for (int j = 0; j < 8; ++j) {
                    acc[0][j] += coef1 * bf2f((unsigned short)b0[j]);
                    acc[1][j] += coef1 * bf2f((unsigned short)b1[j]);
                    acc[2][j] += coef1 * bf2f((unsigned short)b2[j]);
                    acc[3][j] += coef1 * bf2f((unsigned short)b3[j]);
                }
                c0 = n0; c1 = n1;
                e = e2;
            }
            if (e < e1) {
                unsigned cc = csr[e];
                const unsigned short* p0 = xb + (size_t)(cc & 0xFFFFF) * D + q * 8;
                bf16x8 a0 = *(const bf16x8*)(p0);
                bf16x8 a1 = *(const bf16x8*)(p0 + 32);
                bf16x8 a2 = *(const bf16x8*)(p0 + 64);
                bf16x8 a3 = *(const bf16x8*)(p0 + 96);
                float coef0 = dn * rsqrtf((float)(cc >> 20) + 1.0f);
                #pragma unroll
                for (int j = 0; j < 8; ++j) {
                    acc[0][j] += coef0 * bf2f((unsigned short)a0[j]);
                    acc[1][j] += coef0 * bf2f((unsigned short)a1[j]);
                    acc[2][j] += coef0 * bf2f((unsigned short)a2[j]);
                    acc[3][j] += coef0 * bf2f((unsigned short)a3[j]);
                }
            }
        } else {
            #pragma unroll
            for (int m = 0; m < 4; ++m)
                #pragma unroll
                for (int j = 0; j < 8; ++j) acc[m][j] = 0.f;
        }
        #pragma unroll
        for (int m = 0; m < 4; ++m) {
            bf16x8 a;
            #pragma unroll
            for (int j = 0; j < 8; ++j) a[j] = (short)f2bf(acc[m][j]);
            af[conv * 4 + m] = a;
        }
    }

    f32x4 C[8];
    #pragma unroll
    for (int i = 0; i < 8; ++i) C[i] = (f32x4){0.f, 0.f, 0.f, 0.f};
    #pragma unroll
    for (int ks = 0; ks < 8; ++ks) {
        bf16x8 afr = af[ks];          // ks 0..3 -> conv1 k-blocks, 4..7 -> conv2
        #pragma unroll
        for (int ct = 0; ct < 8; ++ct) {
            bf16x8 bfr = *(const bf16x8*)&mlds[ct * 16 + rl][ks * 32 + q * 8];
            C[ct] = __builtin_amdgcn_mfma_f32_16x16x32_bf16(afr, bfr, C[ct], 0, 0, 0);
        }
    }

    // C/D layout: col = lane&15, row = (lane>>4)*4 + reg
    int orow = blockIdx.x * FROWS + wave * 16 + q * 4;
    #pragma unroll
    for (int ct = 0; ct < 8; ++ct) {
        int col = ct * 16 + rl;
        float b = bt[col];
        #pragma unroll
        for (int reg = 0; reg < 4; ++reg) {
            int row = orow + reg;
            if (row < N_NODES) out[(long long)row * D + col] = C[ct][reg] + b;
        }
    }
}

extern "C" void kernel_launch(void* const* d_in, const int* in_sizes, int n_in,
                              void* d_out, int out_size, void* d_ws, size_t ws_size,
                              hipStream_t stream) {
    const float* x      = (const float*)d_in[0];
    const void*  e_pos  = d_in[1];
    const void*  e_neg  = d_in[2];
    const float* W1     = (const float*)d_in[3];
    const float* b1     = (const float*)d_in[4];
    const float* W2     = (const float*)d_in[5];
    const float* b2     = (const float*)d_in[6];
    const float* weight = (const float*)d_in[7];
    const float* bias   = (const float*)d_in[8];
    float* out = (float*)d_out;

    // ---- workspace layout (~33 MB) ----
    unsigned short* xb = (unsigned short*)d_ws;          // N*D bf16
    unsigned short* Mt = xb + (size_t)N_NODES * D;       // 128*256
    float* bt   = (float*)(Mt + 128 * 256);              // D
    float* dinv = bt + D;                                // NT
    int*   degi = (int*)(dinv + NT);                     // NT
    int*   off  = degi + NT;                             // NT+4 (pad)
    int*   bsum = off + NT + 4;                          // 1024
    unsigned char* degb = (unsigned char*)(bsum + 1024); // NT bytes
    unsigned* csr = (unsigned*)(degb + NT);              // ET (4B entries)

    hipMemsetAsync(degi, 0, NT * sizeof(int), stream);
    prep_x2bf_degree<<<129 + XBLK + EGRID, 256, 0, stream>>>(
        W1, W2, weight, b1, b2, bias, x, xb, e_pos, e_neg, Mt, bt, degi);
    scan_pass1<<<NBLK2, SCAN_B, 0, stream>>>(degi, bsum, dinv, degb);
    scan_pass3<<<NBLK2, SCAN_B, 0, stream>>>(degi, bsum, off);
    csr_fill_xcd<<<NPART * CBLK, 256, 0, stream>>>(e_pos, e_neg, off, degi, degb, csr);
    fused_gather_gemm<<<FBLK, 1024, 0, stream>>>(off, csr, xb, dinv, Mt, bt, out);
}